// Round 1
// 493.121 us; speedup vs baseline: 1.0894x; 1.0894x over previous
//
#include <hip/hip_runtime.h>
#include <stdint.h>

#define N_NODES 50000
#define N_EDGES 800000
#define NODE_TILES 782              // ceil(50000/64)

#define SE   72    // e-tile stride (bf16)
#define SW2  72
#define SPQ  136   // pq kernel strides (K=128)
#define SN1  200   // Wn1T row stride (K=192)
#define SN2  264   // Wn2T row stride (K=256)
#define SAG  72    // agg LDS tile stride
#define SH1  264   // h1 LDS tile stride
#define ATS  32    // edge A-tile row stride (K=32, k>=16 zero)

typedef short bf16x8 __attribute__((ext_vector_type(8)));
typedef short short4v __attribute__((ext_vector_type(4)));
typedef unsigned short ushort8 __attribute__((ext_vector_type(8)));
typedef float f32x4  __attribute__((ext_vector_type(4)));

static __device__ __forceinline__ unsigned short f2bf(float f) {
  unsigned int x = __float_as_uint(f);
  unsigned int r = (x + 0x7fffu + ((x >> 16) & 1u)) >> 16;
  return (unsigned short)r;
}
static __device__ __forceinline__ float bf2f(unsigned short u) {
  return __uint_as_float(((unsigned int)u) << 16);
}
// silu via v_rcp_f32: avoids the full-precision fdiv expansion (~8-10 VALU ops)
static __device__ __forceinline__ float silu_f(float x) {
  return x * __builtin_amdgcn_rcpf(1.0f + __expf(-x));
}
static __device__ __forceinline__ float sigmoid_f(float x) {
  return __builtin_amdgcn_rcpf(1.0f + __expf(-x));
}
// packed f32x2 -> bf16x2 (RNE), 1 instr instead of 2x4-op emulation
static __device__ __forceinline__ unsigned int cvt_pk_bf16(float lo, float hi) {
  unsigned int r;
  asm("v_cvt_pk_bf16_f32 %0, %1, %2" : "=v"(r) : "v"(lo), "v"(hi));
  return r;
}
static __device__ __forceinline__ bf16x8 pack8(float4 u, float4 v) {
  bf16x8 w;
  w[0] = (short)f2bf(u.x); w[1] = (short)f2bf(u.y);
  w[2] = (short)f2bf(u.z); w[3] = (short)f2bf(u.w);
  w[4] = (short)f2bf(v.x); w[5] = (short)f2bf(v.y);
  w[6] = (short)f2bf(v.z); w[7] = (short)f2bf(v.w);
  return w;
}

// ---------------------------------------------------------------------------
// prep: natural transposed bf16 weights + destination histogram.
// WrT: 64 x 32 bf16 B-operand for the rank-10+bias tail of layer 1.
//   k0,k1 = w[256]  (d2_hi, d2_lo features)
//   k2,k3 = w[257]  (dl_hi, dl_lo)
//   k4..11 = w[258+c] (struct)
//   k12 = be1; k13 = w256 - bf16(w256); k14 = w257 resid; k15 = be1 resid
// ---------------------------------------------------------------------------
__global__ void prep_hist(
    const int* __restrict__ eidx,
    const float* __restrict__ We1, const float* __restrict__ be1,
    const float* __restrict__ We2,
    const float* __restrict__ Wn1, const float* __restrict__ Wn2,
    unsigned short* __restrict__ WpqT, unsigned short* __restrict__ We2T,
    unsigned short* __restrict__ Wn1T, unsigned short* __restrict__ Wn2T,
    unsigned short* __restrict__ WrT,
    int* __restrict__ cnt)
{
  const int gid = blockIdx.x * 256 + threadIdx.x;
  const int gsz = gridDim.x * 256;
  for (int i = gid; i < 128 * SPQ; i += gsz) {
    int n = i / SPQ, k = i % SPQ;
    unsigned short v = 0;
    if (k < 128) v = (n < 64) ? f2bf(We1[k * 64 + n]) : f2bf(We1[(128 + k) * 64 + (n - 64)]);
    WpqT[i] = v;
  }
  for (int i = gid; i < 64 * SW2; i += gsz) {
    int n = i / SW2, k = i % SW2;
    We2T[i] = (k < 64) ? f2bf(We2[k * 64 + n]) : (unsigned short)0;
  }
  for (int i = gid; i < 256 * SN1; i += gsz) {
    int n = i / SN1, k = i % SN1;
    Wn1T[i] = (k < 192) ? f2bf(Wn1[k * 256 + n]) : (unsigned short)0;
  }
  for (int i = gid; i < 128 * SN2; i += gsz) {
    int n = i / SN2, k = i % SN2;
    Wn2T[i] = (k < 256) ? f2bf(Wn2[k * 128 + n]) : (unsigned short)0;
  }
  for (int i = gid; i < 64 * 32; i += gsz) {
    int n = i >> 5, k = i & 31;
    float v = 0.f;
    if (k < 2)       v = We1[256 * 64 + n];
    else if (k < 4)  v = We1[257 * 64 + n];
    else if (k < 12) v = We1[(258 + (k - 4)) * 64 + n];
    else if (k == 12) v = be1[n];
    else if (k == 13) { float w = We1[256 * 64 + n]; v = w - bf2f(f2bf(w)); }
    else if (k == 14) { float w = We1[257 * 64 + n]; v = w - bf2f(f2bf(w)); }
    else if (k == 15) { float w = be1[n];            v = w - bf2f(f2bf(w)); }
    WrT[i] = (k < 16) ? f2bf(v) : (unsigned short)0;
  }
  if (gid < N_EDGES) atomicAdd(&cnt[eidx[gid]], 1);
}

// ---------------------------------------------------------------------------
// scan: exclusive prefix of cnt -> rowptr[50001], cursor copy. 1 block.
// ---------------------------------------------------------------------------
__global__ __launch_bounds__(1024) void scan_kernel(
    const int* __restrict__ cnt, int* __restrict__ rowptr,
    int* __restrict__ cursor)
{
  __shared__ int wsum[16], woff[16];
  const int t = threadIdx.x;
  const int lane = t & 63, wid = t >> 6;
  const int base = t * 49;
  int loc[49];
  int s = 0;
  #pragma unroll
  for (int i = 0; i < 49; ++i) {
    int idx = base + i;
    int c = (idx < N_NODES) ? cnt[idx] : 0;
    loc[i] = s; s += c;
  }
  int v = s;
  #pragma unroll
  for (int o = 1; o < 64; o <<= 1) {
    int u = __shfl_up(v, o);
    if (lane >= o) v += u;
  }
  if (lane == 63) wsum[wid] = v;
  __syncthreads();
  if (t == 0) {
    int a = 0;
    for (int w = 0; w < 16; ++w) { woff[w] = a; a += wsum[w]; }
    rowptr[N_NODES] = a;
  }
  __syncthreads();
  const int texcl = woff[wid] + (v - s);
  #pragma unroll
  for (int i = 0; i < 49; ++i) {
    int idx = base + i;
    if (idx < N_NODES) {
      int r = texcl + loc[i];
      rowptr[idx] = r;
      cursor[idx] = r;
    }
  }
}

// ---------------------------------------------------------------------------
// fill: order[slot] = edge id (4-B scatter only).
// ---------------------------------------------------------------------------
__global__ void fill_kernel(const int* __restrict__ eidx,
                            int* __restrict__ cursor, int* __restrict__ order)
{
  int e = blockIdx.x * 256 + threadIdx.x;
  if (e < N_EDGES) {
    int d = eidx[e];
    int pos = atomicAdd(&cursor[d], 1);
    order[pos] = e;
  }
}

// ---------------------------------------------------------------------------
// reorder (R5-measured): one thread per CSR slot. Gathers per-edge metadata
// into slot order (sequential writes); computes d2/delta + gate MLP here.
// ---------------------------------------------------------------------------
__global__ void reorder_kernel(
    const int* __restrict__ eidx, const float* __restrict__ xyz,
    const float* __restrict__ estruct, const float* __restrict__ erest,
    const int* __restrict__ order,
    const float* __restrict__ Wg1, const float* __restrict__ bg1,
    const float* __restrict__ Wg2, const float* __restrict__ bg2,
    float4* __restrict__ metaA, unsigned short* __restrict__ sst,
    int* __restrict__ in_s)
{
  int s = blockIdx.x * 256 + threadIdx.x;
  if (s >= N_EDGES) return;
  int e = order[s];
  int i = eidx[e], j = eidx[N_EDGES + e];
  float dx = xyz[i * 3 + 0] - xyz[j * 3 + 0];
  float dy = xyz[i * 3 + 1] - xyz[j * 3 + 1];
  float dz = xyz[i * 3 + 2] - xyz[j * 3 + 2];
  float d2 = dx * dx + dy * dy + dz * dz;
  float dist = sqrtf(d2 + 1e-9f);
  float rest = erest[e];
  float dl = (dist - rest) / (rest + 1e-9f);
  float4 s0 = *(const float4*)&estruct[e * 8];
  float4 s1 = *(const float4*)&estruct[e * 8 + 4];
  float st[8] = {s0.x, s0.y, s0.z, s0.w, s1.x, s1.y, s1.z, s1.w};
  float gsum = 0.f;
  #pragma unroll
  for (int h = 0; h < 32; ++h) {
    float a = bg1[h] + d2 * Wg1[0 * 32 + h] + dl * Wg1[1 * 32 + h];
    #pragma unroll
    for (int c = 0; c < 8; ++c) a += st[c] * Wg1[(2 + c) * 32 + h];
    gsum += silu_f(a) * Wg2[h];
  }
  float g = sigmoid_f(gsum + bg2[0]);
  metaA[s] = make_float4(d2, dl, g, __int_as_float(j));
  ushort8 w;
  #pragma unroll
  for (int c = 0; c < 8; ++c) w[c] = f2bf(st[c]);
  *(ushort8*)&sst[(long)s * 8] = w;
  in_s[s] = i;
}

// ---------------------------------------------------------------------------
// pq: [P|Q] = H @ [We1[0:128] | We1[128:256]], bf16, natural layout.
// ---------------------------------------------------------------------------
__global__ __launch_bounds__(256, 2) void pq_kernel(
    const float* __restrict__ H, const unsigned short* __restrict__ WpqT,
    unsigned short* __restrict__ P, unsigned short* __restrict__ Q)
{
  __shared__ unsigned short As[64 * SPQ];
  __shared__ unsigned short Ws[128 * SPQ];

  const int tid  = threadIdx.x;
  const int lane = tid & 63;
  const int wv   = tid >> 6;
  const int lr   = lane & 15;
  const int lq   = lane >> 4;
  const int m0   = wv * 16;
  const int n0   = blockIdx.x * 64;

  for (int i = tid * 8; i < 128 * SPQ; i += 256 * 8)
    *(bf16x8*)&Ws[i] = *(const bf16x8*)&WpqT[i];
  {
    int le = tid >> 2, q = tid & 3;
    int node = n0 + le; if (node >= N_NODES) node = N_NODES - 1;
    const float* src = H + (long)node * 128 + q * 32;
    unsigned short* dst = &As[le * SPQ + q * 32];
    #pragma unroll
    for (int c = 0; c < 32; c += 8) {
      float4 u = *(const float4*)(src + c);
      float4 v = *(const float4*)(src + c + 4);
      *(bf16x8*)(dst + c) = pack8(u, v);
    }
  }
  __syncthreads();

  f32x4 zero4 = {0.f, 0.f, 0.f, 0.f};
  f32x4 acc[8];
  #pragma unroll
  for (int f = 0; f < 8; ++f) acc[f] = zero4;
  #pragma unroll
  for (int s = 0; s < 4; ++s) {
    int kb = s * 32 + lq * 8;
    bf16x8 a = *(const bf16x8*)&As[(m0 + lr) * SPQ + kb];
    #pragma unroll
    for (int f = 0; f < 8; ++f) {
      bf16x8 b = *(const bf16x8*)&Ws[(f * 16 + lr) * SPQ + kb];
      acc[f] = __builtin_amdgcn_mfma_f32_16x16x32_bf16(a, b, acc[f], 0, 0, 0);
    }
  }
  #pragma unroll
  for (int f = 0; f < 8; ++f) {
    #pragma unroll
    for (int r = 0; r < 4; ++r) {
      int node = n0 + m0 + lq * 4 + r;
      if (node < N_NODES) {
        if (f < 4) P[(long)node * 64 + f * 16 + lr] = f2bf(acc[f][r]);
        else       Q[(long)node * 64 + (f - 4) * 16 + lr] = f2bf(acc[f][r]);
      }
    }
  }
}

// ---------------------------------------------------------------------------
// edge_compute (R6): VALU-bound fix.
//  - rank-10+bias tail of layer1 moved into MFMA (At 16x32 bf16 tile x WrT),
//    split-precision d2/dl + weight-residual slots keep bf16 accuracy.
//  - MFMA operands SWAPPED (W as A-operand): lane output is edge-major with
//    4 consecutive n -> P/Q gathers become 8-B vector loads (1 base per lane),
//    em stores become 8-B vector stores, packing via v_cvt_pk_bf16_f32.
//  - silu via v_rcp instead of full fdiv expansion.
// ---------------------------------------------------------------------------
__global__ __launch_bounds__(256, 4) void edge_compute(
    const unsigned short* __restrict__ P, const unsigned short* __restrict__ Q,
    const int* __restrict__ in_s,
    const float4* __restrict__ metaA, const unsigned short* __restrict__ sst,
    const unsigned short* __restrict__ We2T, const float* __restrict__ be2,
    const unsigned short* __restrict__ WrT,
    unsigned short* __restrict__ em)
{
  __shared__ unsigned short W2s[64 * SW2];      // 9.2 KB
  __shared__ unsigned short Es [4 * 16 * SE];   // 9.2 KB
  __shared__ unsigned short At [4 * 16 * ATS];  // 4.0 KB

  const int tid  = threadIdx.x;
  const int lane = tid & 63;
  const int wv   = tid >> 6;
  const int lr   = lane & 15;
  const int lq   = lane >> 4;

  for (int i = tid * 8; i < 64 * SW2; i += 256 * 8)
    *(bf16x8*)&W2s[i] = *(const bf16x8*)&We2T[i];

  unsigned short* Es_w = &Es[wv * 16 * SE];
  unsigned short* At_w = &At[wv * 16 * ATS];

  // zero the k=16..31 pad of the A-tile once (stays zero forever)
  if (lane < 16) {
    ushort8 z;
    #pragma unroll
    for (int c = 0; c < 8; ++c) z[c] = 0;
    *(ushort8*)&At_w[lane * ATS + 16] = z;
    *(ushort8*)&At_w[lane * ATS + 24] = z;
  }

  // per-lane constants: Wr A-fragments (k>=16 rows are zero) + bias2
  bf16x8 aWr[4];
  float bias2[4][4];
  #pragma unroll
  for (int f = 0; f < 4; ++f) {
    aWr[f] = *(const bf16x8*)&WrT[(f * 16 + lr) * 32 + lq * 8];
    #pragma unroll
    for (int r = 0; r < 4; ++r) bias2[f][r] = be2[f * 16 + lq * 4 + r];
  }
  __syncthreads();

  f32x4 zero4 = {0.f, 0.f, 0.f, 0.f};
  const int n_tiles = N_EDGES / 16;  // 50000
  for (int tile = blockIdx.x * 4 + wv; tile < n_tiles; tile += gridDim.x * 4) {
    const int s0 = tile * 16;

    float4 mm = metaA[s0 + lr];          // x4 broadcast across lq
    int   inode = in_s[s0 + lr];
    int   jnode = __float_as_int(mm.w);
    float g     = mm.z;

    if (lane < 16) {
      ushort8 sv = *(const ushort8*)&sst[(long)(s0 + lane) * 8];
      float d2 = mm.x, dl = mm.y;
      unsigned short d2h = f2bf(d2);
      unsigned short d2l = f2bf(d2 - bf2f(d2h));
      unsigned short dlh = f2bf(dl);
      unsigned short dll = f2bf(dl - bf2f(dlh));
      ushort8 w0, w1;
      w0[0] = d2h;   w0[1] = d2l;   w0[2] = dlh;   w0[3] = dll;
      w0[4] = sv[0]; w0[5] = sv[1]; w0[6] = sv[2]; w0[7] = sv[3];
      w1[0] = sv[4]; w1[1] = sv[5]; w1[2] = sv[6]; w1[3] = sv[7];
      w1[4] = 0x3F80u; w1[5] = d2h; w1[6] = dlh;  w1[7] = 0x3F80u;
      *(ushort8*)&At_w[lane * ATS]     = w0;
      *(ushort8*)&At_w[lane * ATS + 8] = w1;
    }

    // R = meta-tail @ Wr (+be1), output: n = f*16+lq*4+r, edge = lr
    bf16x8 bA = *(const bf16x8*)&At_w[lr * ATS + lq * 8];
    f32x4 acc1[4];
    #pragma unroll
    for (int f = 0; f < 4; ++f)
      acc1[f] = __builtin_amdgcn_mfma_f32_16x16x32_bf16(aWr[f], bA, zero4, 0, 0, 0);

    // finish layer 1: e = silu(P[i] + Q[j] + R), vector 8-B gathers
    const unsigned short* Pb = P + (long)inode * 64;
    const unsigned short* Qb = Q + (long)jnode * 64;
    #pragma unroll
    for (int f = 0; f < 4; ++f) {
      short4v pv = *(const short4v*)&Pb[f * 16 + lq * 4];
      short4v qv = *(const short4v*)&Qb[f * 16 + lq * 4];
      float v0 = silu_f(bf2f((unsigned short)pv[0]) + bf2f((unsigned short)qv[0]) + acc1[f][0]);
      float v1 = silu_f(bf2f((unsigned short)pv[1]) + bf2f((unsigned short)qv[1]) + acc1[f][1]);
      float v2 = silu_f(bf2f((unsigned short)pv[2]) + bf2f((unsigned short)qv[2]) + acc1[f][2]);
      float v3 = silu_f(bf2f((unsigned short)pv[3]) + bf2f((unsigned short)qv[3]) + acc1[f][3]);
      uint2 w;
      w.x = cvt_pk_bf16(v0, v1);
      w.y = cvt_pk_bf16(v2, v3);
      *(uint2*)&Es_w[lr * SE + f * 16 + lq * 4] = w;   // ds_write_b64
    }

    // layer 2: acc2[f][r] = (e @ We2)[edge lr][n = f*16+lq*4+r]
    f32x4 acc2[4];
    #pragma unroll
    for (int f = 0; f < 4; ++f) acc2[f] = zero4;
    #pragma unroll
    for (int s = 0; s < 2; ++s) {
      int kb = s * 32 + lq * 8;
      bf16x8 bE = *(const bf16x8*)&Es_w[lr * SE + kb];
      #pragma unroll
      for (int f = 0; f < 4; ++f) {
        bf16x8 aW = *(const bf16x8*)&W2s[(f * 16 + lr) * SW2 + kb];
        acc2[f] = __builtin_amdgcn_mfma_f32_16x16x32_bf16(aW, bE, acc2[f], 0, 0, 0);
      }
    }

    // epilogue: silu, gate, 8-B vector stores (edge-major)
    unsigned short* emp = em + (long)(s0 + lr) * 64;
    #pragma unroll
    for (int f = 0; f < 4; ++f) {
      float o0 = silu_f(acc2[f][0] + bias2[f][0]) * g;
      float o1 = silu_f(acc2[f][1] + bias2[f][1]) * g;
      float o2 = silu_f(acc2[f][2] + bias2[f][2]) * g;
      float o3 = silu_f(acc2[f][3] + bias2[f][3]) * g;
      uint2 w;
      w.x = cvt_pk_bf16(o0, o1);
      w.y = cvt_pk_bf16(o2, o3);
      *(uint2*)&emp[f * 16 + lq * 4] = w;
    }
  }
}

// ---------------------------------------------------------------------------
// node_fused: phase0 CSR-sum em (sequential, slot-ordered) -> LDS agg tile;
// phase1 h1 = silu([H|agg]@Wn1+bn1) -> LDS transpose; phase2 upd + residual
// + LayerNorm. Weights streamed from L2 (no weight LDS). 43 KB -> 3 blk/CU.
// ---------------------------------------------------------------------------
__global__ __launch_bounds__(256, 3) void node_fused_kernel(
    const float* __restrict__ H, const unsigned short* __restrict__ em,
    const int* __restrict__ rowptr,
    const unsigned short* __restrict__ Wn1T, const float* __restrict__ bn1,
    const unsigned short* __restrict__ Wn2T, const float* __restrict__ bn2,
    const float* __restrict__ ln_g, const float* __restrict__ ln_b,
    float* __restrict__ out)
{
  __shared__ unsigned short aggt[64 * SAG];  // 9.2 KB
  __shared__ unsigned short h1t [64 * SH1];  // 33.8 KB

  const int tid  = threadIdx.x;
  const int lane = tid & 63;
  const int wv   = tid >> 6;
  const int lr   = lane & 15;
  const int lq   = lane >> 4;
  const int m0   = wv * 16;
  const int n0   = blockIdx.x * 64;

  // ---- phase 0: aggregate em rows (sequential CSR range per node) ----
  {
    int le = tid >> 2, q = tid & 3;
    int node = n0 + le;
    float a16[16];
    #pragma unroll
    for (int c = 0; c < 16; ++c) a16[c] = 0.f;
    if (node < N_NODES) {
      int p0 = rowptr[node], p1 = rowptr[node + 1];
      for (int p = p0; p < p1; ++p) {
        const unsigned short* row = em + (long)p * 64 + q * 16;
        ushort8 a = *(const ushort8*)row;
        ushort8 b = *(const ushort8*)(row + 8);
        #pragma unroll
        for (int c = 0; c < 8; ++c) a16[c]     += bf2f(a[c]);
        #pragma unroll
        for (int c = 0; c < 8; ++c) a16[8 + c] += bf2f(b[c]);
      }
    }
    ushort8 w0, w1;
    #pragma unroll
    for (int c = 0; c < 8; ++c) { w0[c] = f2bf(a16[c]); w1[c] = f2bf(a16[8 + c]); }
    *(ushort8*)&aggt[le * SAG + q * 16]     = w0;
    *(ushort8*)&aggt[le * SAG + q * 16 + 8] = w1;
  }
  __syncthreads();

  // ---- phase 1: h1 tile ----
  int rowa = n0 + m0 + lr;
  int rowc = rowa < N_NODES ? rowa : N_NODES - 1;

  f32x4 zero4 = {0.f, 0.f, 0.f, 0.f};
  f32x4 acc1[16];
  #pragma unroll
  for (int f = 0; f < 16; ++f) acc1[f] = zero4;
  #pragma unroll
  for (int s = 0; s < 6; ++s) {
    int kb = s * 32 + lq * 8;
    bf16x8 a;
    if (s < 4) {
      const float* p = H + (long)rowc * 128 + kb;
      float4 u = *(const float4*)p;
      float4 v = *(const float4*)(p + 4);
      a = pack8(u, v);
    } else {
      a = *(const bf16x8*)&aggt[(m0 + lr) * SAG + (kb - 128)];
    }
    #pragma unroll
    for (int f = 0; f < 16; ++f) {
      bf16x8 b = *(const bf16x8*)&Wn1T[(long)(f * 16 + lr) * SN1 + kb];
      acc1[f] = __builtin_amdgcn_mfma_f32_16x16x32_bf16(a, b, acc1[f], 0, 0, 0);
    }
  }
  #pragma unroll
  for (int f = 0; f < 16; ++f) {
    float bias = bn1[f * 16 + lr];
    #pragma unroll
    for (int r = 0; r < 4; ++r)
      h1t[(m0 + lq * 4 + r) * SH1 + f * 16 + lr] = f2bf(silu_f(acc1[f][r] + bias));
  }
  __syncthreads();

  // ---- phase 2: upd + residual + LayerNorm ----
  f32x4 acc2[8];
  #pragma unroll
  for (int f = 0; f < 8; ++f) acc2[f] = zero4;
  #pragma unroll
  for (int s = 0; s < 8; ++s) {
    int kb = s * 32 + lq * 8;
    bf16x8 a = *(const bf16x8*)&h1t[(m0 + lr) * SH1 + kb];
    #pragma unroll
    for (int f = 0; f < 8; ++f) {
      bf16x8 b = *(const bf16x8*)&Wn2T[(long)(f * 16 + lr) * SN2 + kb];
      acc2[f] = __builtin_amdgcn_mfma_f32_16x16x32_bf16(a, b, acc2[f], 0, 0, 0);
    }
  }

  #pragma unroll
  for (int r = 0; r < 4; ++r) {
    int node = n0 + m0 + lq * 4 + r;
    int nc = node < N_NODES ? node : N_NODES - 1;
    float x[8];
    float sum = 0.f, sumsq = 0.f;
    #pragma unroll
    for (int f = 0; f < 8; ++f) {
      int n = f * 16 + lr;
      float u = acc2[f][r] + bn2[n];
      float xv = H[(long)nc * 128 + n] + u;
      x[f] = xv;
      sum += xv;
      sumsq += xv * xv;
    }
    #pragma unroll
    for (int o = 1; o < 16; o <<= 1) {
      sum   += __shfl_xor(sum, o);
      sumsq += __shfl_xor(sumsq, o);
    }
    float mu  = sum * (1.f / 128.f);
    float var = sumsq * (1.f / 128.f) - mu * mu;
    float rstd = rsqrtf(var + 1e-5f);
    if (node < N_NODES) {
      #pragma unroll
      for (int f = 0; f < 8; ++f) {
        int n = f * 16 + lr;
        out[(long)node * 128 + n] = (x[f] - mu) * rstd * ln_g[n] + ln_b[n];
      }
    }
  }
}

extern "C" void kernel_launch(void* const* d_in, const int* in_sizes, int n_in,
                              void* d_out, int out_size, void* d_ws, size_t ws_size,
                              hipStream_t stream) {
  const float* H       = (const float*)d_in[0];
  const float* xyz     = (const float*)d_in[1];
  const int*   eidx    = (const int*)d_in[2];
  const float* estruct = (const float*)d_in[3];
  const float* erest   = (const float*)d_in[4];
  const float* We1     = (const float*)d_in[5];
  const float* be1     = (const float*)d_in[6];
  const float* We2     = (const float*)d_in[7];
  const float* be2     = (const float*)d_in[8];
  const float* Wg1     = (const float*)d_in[9];
  const float* bg1     = (const float*)d_in[10];
  const float* Wg2     = (const float*)d_in[11];
  const float* bg2     = (const float*)d_in[12];
  const float* Wn1     = (const float*)d_in[13];
  const float* bn1     = (const float*)d_in[14];
  const float* Wn2     = (const float*)d_in[15];
  const float* bn2     = (const float*)d_in[16];
  const float* ln_g    = (const float*)d_in[17];
  const float* ln_b    = (const float*)d_in[18];

  char* ws = (char*)d_ws;
  unsigned short* em     = (unsigned short*)(ws + 0);           // 102,400,000
  float4*         metaA  = (float4*)(ws + 102400000);           //  12,800,000
  unsigned short* sst    = (unsigned short*)(ws + 115200000);   //  12,800,000
  int*            in_s   = (int*)(ws + 128000000);              //   3,200,000
  int*            order  = (int*)(ws + 131200000);              //   3,200,000 (dead after reorder)
  unsigned short* P      = (unsigned short*)(ws + 131200000);   //   6,400,000 (aliases order; pq runs after reorder)
  unsigned short* Qm     = (unsigned short*)(ws + 137600000);   //   6,400,000
  int*            cnt    = (int*)(ws + 144000000);              //     200,192
  int*            rowptr = (int*)(ws + 144200192);              //     200,192
  int*            cursor = (int*)(ws + 144400384);              //     200,192
  unsigned short* WpqT   = (unsigned short*)(ws + 144600576);   //      34,816
  unsigned short* We2T   = (unsigned short*)(ws + 144635392);   //       9,216
  unsigned short* Wn1T   = (unsigned short*)(ws + 144644608);   //     102,400
  unsigned short* Wn2T   = (unsigned short*)(ws + 144747008);   //      67,584
  unsigned short* WrT    = (unsigned short*)(ws + 144814592);   //       4,096
  float* out = (float*)d_out;

  hipMemsetAsync(cnt, 0, (size_t)N_NODES * sizeof(int), stream);

  hipLaunchKernelGGL(prep_hist, dim3(3125), dim3(256), 0, stream,
                     eidx, We1, be1, We2, Wn1, Wn2, WpqT, We2T, Wn1T, Wn2T, WrT, cnt);
  hipLaunchKernelGGL(scan_kernel, dim3(1), dim3(1024), 0, stream,
                     cnt, rowptr, cursor);
  hipLaunchKernelGGL(fill_kernel, dim3(3125), dim3(256), 0, stream,
                     eidx, cursor, order);
  hipLaunchKernelGGL(reorder_kernel, dim3(3125), dim3(256), 0, stream,
                     eidx, xyz, estruct, erest, order,
                     Wg1, bg1, Wg2, bg2, metaA, sst, in_s);
  hipLaunchKernelGGL(pq_kernel, dim3(NODE_TILES), dim3(256), 0, stream,
                     H, WpqT, P, Qm);
  hipLaunchKernelGGL(edge_compute, dim3(1024), dim3(256), 0, stream,
                     P, Qm, in_s, metaA, sst, We2T, be2, WrT, em);
  hipLaunchKernelGGL(node_fused_kernel, dim3(NODE_TILES), dim3(256), 0, stream,
                     H, em, rowptr, Wn1T, bn1, Wn2T, bn2, ln_g, ln_b, out);
}